// Round 3
// baseline (1439.306 us; speedup 1.0000x reference)
//
#include <hip/hip_runtime.h>
#include <hip/hip_bf16.h>

// ---------------------------------------------------------------------------
// GNNEncoder: 2x TransformerConv (heads=1) + ReLU.
// R8 (from R7):
//   attn is latency-limited (BW scaled with in-flight bytes R6->R7 at equal
//   occupancy; VALUBusy 17%). So:
//     - attn: launch_bounds(256,8), grid 2048 blocks -> 32 waves/CU (was 20).
//     - k|v interleaved in one kvb[node][256] bf16 row (both gathers hit the
//       same 512 B region; pre_mfma writes both halves at col c-128).
//   Everything else unchanged from R7.
// ---------------------------------------------------------------------------

#define D 128
#define ED 64

typedef short bf16x8 __attribute__((ext_vector_type(8)));
typedef float f32x4  __attribute__((ext_vector_type(4)));

static __device__ __forceinline__ unsigned short f2bf(float f) {
    unsigned int u = __float_as_uint(f);
    u = (u + 0x7fffu + ((u >> 16) & 1u)) >> 16;   // round-to-nearest-even
    return (unsigned short)u;
}
static __device__ __forceinline__ float bf2f(unsigned short u) {
    return __uint_as_float((unsigned int)u << 16);
}

// ---------------- fuse We into Wq: Wqe[i][c] = sum_j Wq[i][j]*We[c][j] -----
__global__ __launch_bounds__(128) void fuse_we_kernel(
    const float* __restrict__ Wq, const float* __restrict__ bq,
    const float* __restrict__ We,
    float* __restrict__ Wqe, float* __restrict__ bqe)
{
    __shared__ float WeL[ED * (D + 1)];
    const int tid = threadIdx.x;
    for (int i = tid; i < ED * D; i += 128) {
        int c = i >> 7, j = i & (D - 1);
        WeL[c * (D + 1) + j] = We[i];
    }
    __syncthreads();
    const int c = tid & 63;
    if (blockIdx.x == 64) {
        if (tid < 64) {
            float acc = 0.f;
            for (int j = 0; j < D; ++j) acc += bq[j] * WeL[c * (D + 1) + j];
            bqe[c] = acc;
        }
        return;
    }
    const int ii = blockIdx.x * 2 + (tid >> 6);
    const float* wrow = Wq + (size_t)ii * D;
    float acc = 0.f;
#pragma unroll 4
    for (int j = 0; j < D; ++j) acc += wrow[j] * WeL[c * (D + 1) + j];
    Wqe[(size_t)ii * ED + c] = acc;
}

// ---------------- pack weights into MFMA B-fragment bf16 layout ------------
// Bp[((kb*576 + n)*4 + quad)*8 + j] = Wcat[kb*32 + quad*8 + j][n]  (bf16)
// bias[576] = [bq|bk|bv|bs|bqe]
__global__ __launch_bounds__(256) void pack_weights_kernel(
    const float* __restrict__ Wq, const float* __restrict__ Wk,
    const float* __restrict__ Wv, const float* __restrict__ Ws,
    const float* __restrict__ Wqe,
    const float* __restrict__ bq, const float* __restrict__ bk,
    const float* __restrict__ bv, const float* __restrict__ bs,
    const float* __restrict__ bqe,
    unsigned short* __restrict__ Bp, float* __restrict__ bias)
{
    const int i = blockIdx.x * 256 + threadIdx.x;
    if (i < 9216) {
        const int kb = i / 2304;
        const int rem = i - kb * 2304;
        const int n = rem >> 2;
        const int quad = rem & 3;
        const int k0 = kb * 32 + quad * 8;
        const float* src; int cl, stride;
        if (n < 128)      { src = Wq;  cl = n;       stride = 128; }
        else if (n < 256) { src = Wk;  cl = n - 128; stride = 128; }
        else if (n < 384) { src = Wv;  cl = n - 256; stride = 128; }
        else if (n < 512) { src = Ws;  cl = n - 384; stride = 128; }
        else              { src = Wqe; cl = n - 512; stride = 64;  }
        unsigned int w[4];
#pragma unroll
        for (int p = 0; p < 4; ++p) {
            unsigned short lo = f2bf(src[(size_t)(k0 + 2 * p) * stride + cl]);
            unsigned short hi = f2bf(src[(size_t)(k0 + 2 * p + 1) * stride + cl]);
            w[p] = (unsigned int)lo | ((unsigned int)hi << 16);
        }
        ((uint4*)Bp)[i] = make_uint4(w[0], w[1], w[2], w[3]);
    } else if (i < 9216 + 576) {
        const int c = i - 9216;
        float b;
        if (c < 128)      b = bq[c];
        else if (c < 256) b = bk[c - 128];
        else if (c < 384) b = bv[c - 256];
        else if (c < 512) b = bs[c - 384];
        else              b = bqe[c - 512];
        bias[c] = b;
    }
}

// ---------------- cast x (fp32) -> bf16 row-major --------------------------
__global__ __launch_bounds__(256) void cast_x_kernel(
    const float* __restrict__ x, unsigned short* __restrict__ xb, int n8)
{
    const int i = blockIdx.x * 256 + threadIdx.x;
    if (i >= n8) return;
    const float4 a = ((const float4*)x)[i * 2];
    const float4 b = ((const float4*)x)[i * 2 + 1];
    uint4 o;
    o.x = (unsigned int)f2bf(a.x) | ((unsigned int)f2bf(a.y) << 16);
    o.y = (unsigned int)f2bf(a.z) | ((unsigned int)f2bf(a.w) << 16);
    o.z = (unsigned int)f2bf(b.x) | ((unsigned int)f2bf(b.y) << 16);
    o.w = (unsigned int)f2bf(b.z) | ((unsigned int)f2bf(b.w) << 16);
    ((uint4*)xb)[i] = o;
}

// ---------------- MFMA pre-GEMM: [N x 128] @ [128 x 576] -------------------
// grid (ceil(N/64), 2); 256 thr = 4 waves; wave does 16 rows x 288 cols.
// q, skip, qe in fp32; k|v interleaved bf16 kvb[N][256] (k: 0..127, v: 128..255).
__global__ __launch_bounds__(256) void pre_mfma_kernel(
    const unsigned short* __restrict__ xb, const unsigned short* __restrict__ Bp,
    const float* __restrict__ bias,
    float* __restrict__ q, unsigned short* __restrict__ kvb,
    float* __restrict__ skip, float* __restrict__ qe, int n_nodes)
{
    const int wave = threadIdx.x >> 6, lane = threadIdx.x & 63;
    const int l16 = lane & 15, quad = lane >> 4;
    const int row0 = blockIdx.x * 64 + wave * 16;

    const unsigned short* xr = xb + (size_t)(row0 + l16) * 128 + quad * 8;
    bf16x8 A[4];
#pragma unroll
    for (int kk = 0; kk < 4; ++kk) A[kk] = *(const bf16x8*)(xr + kk * 32);

    const int t0 = blockIdx.y * 18;
    f32x4 acc[18];
#pragma unroll
    for (int t = 0; t < 18; ++t) acc[t] = (f32x4){0.f, 0.f, 0.f, 0.f};

#pragma unroll
    for (int t = 0; t < 18; ++t) {
        const unsigned short* bp = Bp + (size_t)((((t0 + t) * 16 + l16) * 4 + quad)) * 8;
#pragma unroll
        for (int kk = 0; kk < 4; ++kk) {
            bf16x8 B = *(const bf16x8*)(bp + kk * 18432);
            acc[t] = __builtin_amdgcn_mfma_f32_16x16x32_bf16(A[kk], B, acc[t], 0, 0, 0);
        }
    }

#pragma unroll
    for (int t = 0; t < 18; ++t) {
        const int c = (t0 + t) * 16 + l16;
        const float bia = bias[c];
        if (c >= 128 && c < 384) {
            const int cl = c - 128;   // k -> cols 0..127, v -> cols 128..255
#pragma unroll
            for (int r = 0; r < 4; ++r) {
                const int gr = row0 + quad * 4 + r;
                if (gr < n_nodes) kvb[(size_t)gr * 256 + cl] = f2bf(acc[t][r] + bia);
            }
        } else {
            float* dst; int cl, stride;
            if (c < 128)      { dst = q;    cl = c;       stride = 128; }
            else if (c < 512) { dst = skip; cl = c - 384; stride = 128; }
            else              { dst = qe;   cl = c - 512; stride = 64;  }
#pragma unroll
            for (int r = 0; r < 4; ++r) {
                const int gr = row0 + quad * 4 + r;
                if (gr < n_nodes) dst[(size_t)gr * stride + cl] = acc[t][r] + bia;
            }
        }
    }
}

// ---------------- CSR build ------------------------------------------------
__global__ __launch_bounds__(256) void hist_kernel(
    const int* __restrict__ ei, int* __restrict__ cnt, int nE)
{
    int e = blockIdx.x * 256 + threadIdx.x;
    if (e >= nE) return;
    atomicAdd(&cnt[ei[nE + e]], 1);
}

__global__ __launch_bounds__(256) void scan1_kernel(
    const int* __restrict__ cnt, int* __restrict__ offs,
    int* __restrict__ blksum, int n)
{
    __shared__ int tmp[256];
    const int t = threadIdx.x;
    const int base = blockIdx.x * 1024 + t * 4;
    int v0 = (base + 0 < n) ? cnt[base + 0] : 0;
    int v1 = (base + 1 < n) ? cnt[base + 1] : 0;
    int v2 = (base + 2 < n) ? cnt[base + 2] : 0;
    int v3 = (base + 3 < n) ? cnt[base + 3] : 0;
    const int s = v0 + v1 + v2 + v3;
    tmp[t] = s;
    __syncthreads();
    for (int ofs = 1; ofs < 256; ofs <<= 1) {
        int val = (t >= ofs) ? tmp[t - ofs] : 0;
        __syncthreads();
        tmp[t] += val;
        __syncthreads();
    }
    const int excl = tmp[t] - s;
    if (base + 0 < n) offs[base + 0] = excl;
    if (base + 1 < n) offs[base + 1] = excl + v0;
    if (base + 2 < n) offs[base + 2] = excl + v0 + v1;
    if (base + 3 < n) offs[base + 3] = excl + v0 + v1 + v2;
    if (t == 255) blksum[blockIdx.x] = tmp[255];
}

__global__ __launch_bounds__(64) void scan2_kernel(
    int* __restrict__ offs, int* __restrict__ cursor,
    const int* __restrict__ blksum, int n, int nblk)
{
    const int t = threadIdx.x;
    const int b = blockIdx.x;
    int vb = (t < b) ? blksum[t] : 0;
    int va = (t < nblk) ? blksum[t] : 0;
#pragma unroll
    for (int o = 32; o; o >>= 1) { vb += __shfl_xor(vb, o, 64); va += __shfl_xor(va, o, 64); }
    const int boff = vb;
    for (int i = b * 1024 + t; i < (b + 1) * 1024 && i < n; i += 64) {
        int val = offs[i] + boff;
        offs[i] = val;
        cursor[i] = val;
    }
    if (b == 0 && t == 0) offs[n] = va;
}

// ---------------- scatter: build csrsrc + ea permuted to slot order (bf16) -
// one 16-lane group per edge; lane0 claims the slot, group copies ea row.
__global__ __launch_bounds__(256) void scatter_ea_kernel(
    const int* __restrict__ ei, int* __restrict__ cursor,
    const float* __restrict__ ea,
    int* __restrict__ csrsrc, unsigned short* __restrict__ eac, int nE)
{
    const int g = (blockIdx.x * 256 + threadIdx.x) >> 4;
    if (g >= nE) return;
    const int lane = threadIdx.x & 63;
    const int l16 = lane & 15;
    int slot = 0;
    if (l16 == 0) {
        const int dd = ei[nE + g];
        slot = atomicAdd(&cursor[dd], 1);
        csrsrc[slot] = ei[g];
    }
    slot = __shfl(slot, lane & 48, 64);   // broadcast from group's lane 0
    const float4 e4 = ((const float4*)(ea + (size_t)g * ED))[l16];
    ushort4 o;
    o.x = f2bf(e4.x); o.y = f2bf(e4.y); o.z = f2bf(e4.z); o.w = f2bf(e4.w);
    ((ushort4*)eac)[(size_t)slot * 16 + l16] = o;
}

// ---------------- fused attention: alpha + softmax + aggregate -------------
// persistent waves, 1 node per wave; 16 lanes per edge, 4 edges/slot,
// 3 slots (12 edges) of data in flight, src indices prefetched one loop
// iteration ahead of their dependent kv gathers. 32 waves/CU.
// y = agg/lsum + skip written IN PLACE into skip buffer; t/lsum -> tn.
__global__ __launch_bounds__(256, 8) void attn_kernel(
    const int* __restrict__ rowptr, const int* __restrict__ csrsrc,
    const unsigned short* __restrict__ eac,
    const float* __restrict__ q, const float* __restrict__ qe,
    const unsigned short* __restrict__ kvb,
    float* __restrict__ skip_y, float* __restrict__ tn,
    int n_nodes, int nwaves)
{
    const int tid = threadIdx.x;
    const int lane = tid & 63;
    const int grp = lane >> 4, l16 = lane & 15;
    const int wid = blockIdx.x * 4 + (tid >> 6);

#define AT_LDSRC(P, II) do { \
        const int _i = (II) + grp; \
        P##s = csrsrc[_i < end ? _i : beg]; \
    } while (0)
#define AT_LDDATA(P, II) do { \
        const int _i = (II) + grp; \
        const int _ic = _i < end ? _i : beg; \
        const unsigned short* _kv = kvb + (size_t)P##s * 256 + l16 * 8; \
        P##k = *(const bf16x8*)(_kv); \
        P##v = *(const bf16x8*)(_kv + 128); \
        P##e = ((const ushort4*)eac)[(size_t)_ic * 16 + l16]; \
    } while (0)
#define AT_ACC(P, II) do { \
        const float ef0 = bf2f(P##e.x), ef1 = bf2f(P##e.y); \
        const float ef2 = bf2f(P##e.z), ef3 = bf2f(P##e.w); \
        float _p = qa.x * bf2f((unsigned short)P##k[0]) \
                 + qa.y * bf2f((unsigned short)P##k[1]) \
                 + qa.z * bf2f((unsigned short)P##k[2]) \
                 + qa.w * bf2f((unsigned short)P##k[3]) \
                 + qb.x * bf2f((unsigned short)P##k[4]) \
                 + qb.y * bf2f((unsigned short)P##k[5]) \
                 + qb.z * bf2f((unsigned short)P##k[6]) \
                 + qb.w * bf2f((unsigned short)P##k[7]) \
                 + qe4.x * ef0 + qe4.y * ef1 + qe4.z * ef2 + qe4.w * ef3; \
        _p += __shfl_xor(_p, 8, 64); \
        _p += __shfl_xor(_p, 4, 64); \
        _p += __shfl_xor(_p, 2, 64); \
        _p += __shfl_xor(_p, 1, 64); \
        const float _w = ((II) + grp < end) ? __expf(_p * 0.08838834764831845f) : 0.f; \
        a0 += _w * bf2f((unsigned short)P##v[0]); \
        a1 += _w * bf2f((unsigned short)P##v[1]); \
        a2 += _w * bf2f((unsigned short)P##v[2]); \
        a3 += _w * bf2f((unsigned short)P##v[3]); \
        a4 += _w * bf2f((unsigned short)P##v[4]); \
        a5 += _w * bf2f((unsigned short)P##v[5]); \
        a6 += _w * bf2f((unsigned short)P##v[6]); \
        a7 += _w * bf2f((unsigned short)P##v[7]); \
        t0 += _w * ef0; t1 += _w * ef1; t2 += _w * ef2; t3 += _w * ef3; \
        lsum += _w; \
    } while (0)

    for (int d = wid; d < n_nodes; d += nwaves) {
        const int beg = rowptr[d], end = rowptr[d + 1];
        float a0 = 0, a1 = 0, a2 = 0, a3 = 0, a4 = 0, a5 = 0, a6 = 0, a7 = 0;
        float t0 = 0, t1 = 0, t2 = 0, t3 = 0, lsum = 0;

        const float4 qa  = *(const float4*)(q + (size_t)d * D + l16 * 8);
        const float4 qb  = *(const float4*)(q + (size_t)d * D + l16 * 8 + 4);
        const float4 qe4 = ((const float4*)(qe + (size_t)d * ED))[l16];

        if (beg < end) {
            int As, Bs, Cs;
            bf16x8 Ak, Av, Bk, Bv, Ck, Cv;
            ushort4 Ae, Be, Ce;
            AT_LDSRC(A, beg); AT_LDSRC(B, beg + 4); AT_LDSRC(C, beg + 8);
            AT_LDDATA(A, beg); AT_LDDATA(B, beg + 4); AT_LDDATA(C, beg + 8);
            AT_LDSRC(A, beg + 12); AT_LDSRC(B, beg + 16); AT_LDSRC(C, beg + 20);
            for (int i = beg; i < end; i += 12) {
                AT_ACC(A, i);
                if (i + 12 < end) { AT_LDDATA(A, i + 12); AT_LDSRC(A, i + 24); }
                AT_ACC(B, i + 4);
                if (i + 16 < end) { AT_LDDATA(B, i + 16); AT_LDSRC(B, i + 28); }
                AT_ACC(C, i + 8);
                if (i + 20 < end) { AT_LDDATA(C, i + 20); AT_LDSRC(C, i + 32); }
            }
        }
        // merge the 4 groups
#pragma unroll
        for (int off = 16; off <= 32; off <<= 1) {
            a0 += __shfl_xor(a0, off, 64); a1 += __shfl_xor(a1, off, 64);
            a2 += __shfl_xor(a2, off, 64); a3 += __shfl_xor(a3, off, 64);
            a4 += __shfl_xor(a4, off, 64); a5 += __shfl_xor(a5, off, 64);
            a6 += __shfl_xor(a6, off, 64); a7 += __shfl_xor(a7, off, 64);
            t0 += __shfl_xor(t0, off, 64); t1 += __shfl_xor(t1, off, 64);
            t2 += __shfl_xor(t2, off, 64); t3 += __shfl_xor(t3, off, 64);
            lsum += __shfl_xor(lsum, off, 64);
        }
        const float inv = 1.f / fmaxf(lsum, 1e-16f);
        if (grp == 0) {
            float4* sp = (float4*)(skip_y + (size_t)d * D);
            const float4 s0 = sp[l16 * 2], s1 = sp[l16 * 2 + 1];
            sp[l16 * 2] = make_float4(a0 * inv + s0.x, a1 * inv + s0.y,
                                      a2 * inv + s0.z, a3 * inv + s0.w);
            sp[l16 * 2 + 1] = make_float4(a4 * inv + s1.x, a5 * inv + s1.y,
                                          a6 * inv + s1.z, a7 * inv + s1.w);
        } else if (grp == 1) {
            ((float4*)(tn + (size_t)d * ED))[l16] =
                make_float4(t0 * inv, t1 * inv, t2 * inv, t3 * inv);
        }
    }
#undef AT_LDSRC
#undef AT_LDDATA
#undef AT_ACC
}

// ---------------- epilogue: out = y + t@We (+relu+bf16 for L1) -------------
// block: 256 thr = 16 nodes x 16 col-groups of 8.
template<bool L1>
__global__ __launch_bounds__(256) void out_we_kernel(
    const float* __restrict__ y, const float* __restrict__ tn,
    const float* __restrict__ We, float* __restrict__ outf,
    unsigned short* __restrict__ outb, int n_nodes)
{
    __shared__ float WeS[ED * D];          // 32 KB, [j][c]
    __shared__ float tS[16 * (ED + 1)];    // padded rows
    const int tid = threadIdx.x;
    for (int i = tid; i < ED * D / 4; i += 256)
        ((float4*)WeS)[i] = ((const float4*)We)[i];
    const int n0 = blockIdx.x * 16;
    for (int i = tid; i < 16 * ED; i += 256) {
        const int r = i >> 6, c = i & 63;
        const int n = n0 + r;
        tS[r * (ED + 1) + c] = (n < n_nodes) ? tn[(size_t)n * ED + c] : 0.f;
    }
    __syncthreads();
    const int r = tid >> 4;
    const int n = n0 + r;
    if (n >= n_nodes) return;
    const int c0 = (tid & 15) * 8;
    const float* tr = tS + r * (ED + 1);
    float acc0 = 0, acc1 = 0, acc2 = 0, acc3 = 0, acc4 = 0, acc5 = 0, acc6 = 0, acc7 = 0;
#pragma unroll 8
    for (int j = 0; j < ED; ++j) {
        const float tv = tr[j];
        const float4 wA = *(const float4*)(WeS + j * D + c0);
        const float4 wB = *(const float4*)(WeS + j * D + c0 + 4);
        acc0 += tv * wA.x; acc1 += tv * wA.y; acc2 += tv * wA.z; acc3 += tv * wA.w;
        acc4 += tv * wB.x; acc5 += tv * wB.y; acc6 += tv * wB.z; acc7 += tv * wB.w;
    }
    const float4 yA = *(const float4*)(y + (size_t)n * D + c0);
    const float4 yB = *(const float4*)(y + (size_t)n * D + c0 + 4);
    float r0 = acc0 + yA.x, r1 = acc1 + yA.y, r2 = acc2 + yA.z, r3 = acc3 + yA.w;
    float r4 = acc4 + yB.x, r5 = acc5 + yB.y, r6 = acc6 + yB.z, r7 = acc7 + yB.w;
    if (L1) {
        r0 = fmaxf(r0, 0.f); r1 = fmaxf(r1, 0.f);
        r2 = fmaxf(r2, 0.f); r3 = fmaxf(r3, 0.f);
        r4 = fmaxf(r4, 0.f); r5 = fmaxf(r5, 0.f);
        r6 = fmaxf(r6, 0.f); r7 = fmaxf(r7, 0.f);
        uint4 o;
        o.x = (unsigned int)f2bf(r0) | ((unsigned int)f2bf(r1) << 16);
        o.y = (unsigned int)f2bf(r2) | ((unsigned int)f2bf(r3) << 16);
        o.z = (unsigned int)f2bf(r4) | ((unsigned int)f2bf(r5) << 16);
        o.w = (unsigned int)f2bf(r6) | ((unsigned int)f2bf(r7) << 16);
        ((uint4*)(outb + (size_t)n * D))[tid & 15] = o;
    } else {
        float4* op = (float4*)(outf + (size_t)n * D);
        op[(tid & 15) * 2] = make_float4(r0, r1, r2, r3);
        op[(tid & 15) * 2 + 1] = make_float4(r4, r5, r6, r7);
    }
}

// ---------------------------------------------------------------------------
extern "C" void kernel_launch(void* const* d_in, const int* in_sizes, int n_in,
                              void* d_out, int out_size, void* d_ws, size_t ws_size,
                              hipStream_t stream) {
    const float* x   = (const float*)d_in[0];
    const int*   ei  = (const int*)d_in[1];
    const float* ea  = (const float*)d_in[2];
    const float* Wq1 = (const float*)d_in[3];  const float* bq1 = (const float*)d_in[4];
    const float* Wk1 = (const float*)d_in[5];  const float* bk1 = (const float*)d_in[6];
    const float* Wv1 = (const float*)d_in[7];  const float* bv1 = (const float*)d_in[8];
    const float* We1 = (const float*)d_in[9];
    const float* Ws1 = (const float*)d_in[10]; const float* bs1 = (const float*)d_in[11];
    const float* Wq2 = (const float*)d_in[12]; const float* bq2 = (const float*)d_in[13];
    const float* Wk2 = (const float*)d_in[14]; const float* bk2 = (const float*)d_in[15];
    const float* Wv2 = (const float*)d_in[16]; const float* bv2 = (const float*)d_in[17];
    const float* We2 = (const float*)d_in[18];
    const float* Ws2 = (const float*)d_in[19]; const float* bs2 = (const float*)d_in[20];

    const int N_ = in_sizes[0] / D;
    const int E_ = in_sizes[1] / 2;
    const int Npad = ((N_ + 63) / 64) * 64;

    // workspace layout
    float* ws   = (float*)d_ws;
    float* q    = ws;                                   // [Npad][128] f32
    float* skip = q + (size_t)Npad * D;                 // [Npad][128] f32 (y in place)
    float* qe   = skip + (size_t)Npad * D;              // [Npad][64]  f32
    float* tn   = qe + (size_t)Npad * ED;               // [Npad][64]  f32
    unsigned short* kvb = (unsigned short*)(tn + (size_t)Npad * ED); // [Npad][256] bf16 (k|v)
    unsigned short* xb = kvb + (size_t)Npad * 256;      // [Npad][128] bf16
    unsigned short* Bp1 = xb + (size_t)Npad * D;        // 73728 ushorts
    unsigned short* Bp2 = Bp1 + 73728;
    float* bias1 = (float*)(Bp2 + 73728);
    float* bias2 = bias1 + 576;
    float* Wqe1  = bias2 + 576;
    float* bqe1  = Wqe1 + D * ED;
    float* Wqe2  = bqe1 + ED;
    float* bqe2  = Wqe2 + D * ED;
    unsigned short* eac = (unsigned short*)(bqe2 + ED); // [E][64] bf16, slot order
    int* cnt    = (int*)(eac + (size_t)E_ * ED);
    int* offs   = cnt  + N_;
    int* blksum = offs + N_ + 1;
    int* csrsrc = blksum + 64;                          // [E] int (src only)
    float* out  = (float*)d_out;

    const int eblk256 = (E_ + 255) / 256;
    const int eblk16  = (E_ * 16 + 255) / 256;
    const int sblk    = (N_ + 1023) / 1024;
    const int gpre    = Npad / 64;
    const int ablk    = 2048;                           // 8 blocks/CU x 256 CU = 32 waves/CU
    const int nwaves  = ablk * 4;
    const int oblk    = (N_ + 15) / 16;

    // ---- CSR build + ea permute/cast (shared by both layers) ----
    hipMemsetAsync(cnt, 0, (size_t)N_ * sizeof(int), stream);
    hist_kernel<<<eblk256, 256, 0, stream>>>(ei, cnt, E_);
    scan1_kernel<<<sblk, 256, 0, stream>>>(cnt, offs, blksum, N_);
    scan2_kernel<<<sblk, 64, 0, stream>>>(offs, cnt, blksum, N_, sblk);
    scatter_ea_kernel<<<eblk16, 256, 0, stream>>>(ei, cnt, ea, csrsrc, eac, E_);

    // ---- weight prep ----
    fuse_we_kernel<<<65, 128, 0, stream>>>(Wq1, bq1, We1, Wqe1, bqe1);
    fuse_we_kernel<<<65, 128, 0, stream>>>(Wq2, bq2, We2, Wqe2, bqe2);
    pack_weights_kernel<<<39, 256, 0, stream>>>(Wq1, Wk1, Wv1, Ws1, Wqe1,
                                                bq1, bk1, bv1, bs1, bqe1, Bp1, bias1);
    pack_weights_kernel<<<39, 256, 0, stream>>>(Wq2, Wk2, Wv2, Ws2, Wqe2,
                                                bq2, bk2, bv2, bs2, bqe2, Bp2, bias2);
    cast_x_kernel<<<(N_ * D / 8 + 255) / 256, 256, 0, stream>>>(x, xb, N_ * D / 8);

    // ---- layer 1 ----
    pre_mfma_kernel<<<dim3(gpre, 2), 256, 0, stream>>>(xb, Bp1, bias1,
                                                       q, kvb, skip, qe, N_);
    attn_kernel<<<ablk, 256, 0, stream>>>(offs, csrsrc, eac, q, qe, kvb,
                                          skip, tn, N_, nwaves);
    out_we_kernel<true><<<oblk, 256, 0, stream>>>(skip, tn, We1, nullptr, xb, N_);

    // ---- layer 2 (h lives as bf16 in xb) ----
    pre_mfma_kernel<<<dim3(gpre, 2), 256, 0, stream>>>(xb, Bp2, bias2,
                                                       q, kvb, skip, qe, N_);
    attn_kernel<<<ablk, 256, 0, stream>>>(offs, csrsrc, eac, q, qe, kvb,
                                          skip, tn, N_, nwaves);
    out_we_kernel<false><<<oblk, 256, 0, stream>>>(skip, tn, We2, out, nullptr, N_);
}

// Round 4
// 882.184 us; speedup vs baseline: 1.6315x; 1.6315x over previous
//
#include <hip/hip_runtime.h>
#include <hip/hip_bf16.h>

// ---------------------------------------------------------------------------
// GNNEncoder: 2x TransformerConv (heads=1) + ReLU.
// R9 (from R8 post-mortem):
//   R8's launch_bounds(256,8) forced VGPR 48->32 and spilled the pipeline
//   (FETCH/WRITE x4). R7's 48-VGPR kernel already allowed 8 waves/SIMD;
//   its 51% occupancy was the 1280-block grid cap (62.5% of slots).
//   R9 = R8 with launch_bounds back to (256,5) (proven 48 VGPR), grid kept
//   at 2048 blocks -> 32 waves/CU; kv interleave kept.
// ---------------------------------------------------------------------------

#define D 128
#define ED 64

typedef short bf16x8 __attribute__((ext_vector_type(8)));
typedef float f32x4  __attribute__((ext_vector_type(4)));

static __device__ __forceinline__ unsigned short f2bf(float f) {
    unsigned int u = __float_as_uint(f);
    u = (u + 0x7fffu + ((u >> 16) & 1u)) >> 16;   // round-to-nearest-even
    return (unsigned short)u;
}
static __device__ __forceinline__ float bf2f(unsigned short u) {
    return __uint_as_float((unsigned int)u << 16);
}

// ---------------- fuse We into Wq: Wqe[i][c] = sum_j Wq[i][j]*We[c][j] -----
__global__ __launch_bounds__(128) void fuse_we_kernel(
    const float* __restrict__ Wq, const float* __restrict__ bq,
    const float* __restrict__ We,
    float* __restrict__ Wqe, float* __restrict__ bqe)
{
    __shared__ float WeL[ED * (D + 1)];
    const int tid = threadIdx.x;
    for (int i = tid; i < ED * D; i += 128) {
        int c = i >> 7, j = i & (D - 1);
        WeL[c * (D + 1) + j] = We[i];
    }
    __syncthreads();
    const int c = tid & 63;
    if (blockIdx.x == 64) {
        if (tid < 64) {
            float acc = 0.f;
            for (int j = 0; j < D; ++j) acc += bq[j] * WeL[c * (D + 1) + j];
            bqe[c] = acc;
        }
        return;
    }
    const int ii = blockIdx.x * 2 + (tid >> 6);
    const float* wrow = Wq + (size_t)ii * D;
    float acc = 0.f;
#pragma unroll 4
    for (int j = 0; j < D; ++j) acc += wrow[j] * WeL[c * (D + 1) + j];
    Wqe[(size_t)ii * ED + c] = acc;
}

// ---------------- pack weights into MFMA B-fragment bf16 layout ------------
// Bp[((kb*576 + n)*4 + quad)*8 + j] = Wcat[kb*32 + quad*8 + j][n]  (bf16)
// bias[576] = [bq|bk|bv|bs|bqe]
__global__ __launch_bounds__(256) void pack_weights_kernel(
    const float* __restrict__ Wq, const float* __restrict__ Wk,
    const float* __restrict__ Wv, const float* __restrict__ Ws,
    const float* __restrict__ Wqe,
    const float* __restrict__ bq, const float* __restrict__ bk,
    const float* __restrict__ bv, const float* __restrict__ bs,
    const float* __restrict__ bqe,
    unsigned short* __restrict__ Bp, float* __restrict__ bias)
{
    const int i = blockIdx.x * 256 + threadIdx.x;
    if (i < 9216) {
        const int kb = i / 2304;
        const int rem = i - kb * 2304;
        const int n = rem >> 2;
        const int quad = rem & 3;
        const int k0 = kb * 32 + quad * 8;
        const float* src; int cl, stride;
        if (n < 128)      { src = Wq;  cl = n;       stride = 128; }
        else if (n < 256) { src = Wk;  cl = n - 128; stride = 128; }
        else if (n < 384) { src = Wv;  cl = n - 256; stride = 128; }
        else if (n < 512) { src = Ws;  cl = n - 384; stride = 128; }
        else              { src = Wqe; cl = n - 512; stride = 64;  }
        unsigned int w[4];
#pragma unroll
        for (int p = 0; p < 4; ++p) {
            unsigned short lo = f2bf(src[(size_t)(k0 + 2 * p) * stride + cl]);
            unsigned short hi = f2bf(src[(size_t)(k0 + 2 * p + 1) * stride + cl]);
            w[p] = (unsigned int)lo | ((unsigned int)hi << 16);
        }
        ((uint4*)Bp)[i] = make_uint4(w[0], w[1], w[2], w[3]);
    } else if (i < 9216 + 576) {
        const int c = i - 9216;
        float b;
        if (c < 128)      b = bq[c];
        else if (c < 256) b = bk[c - 128];
        else if (c < 384) b = bv[c - 256];
        else if (c < 512) b = bs[c - 384];
        else              b = bqe[c - 512];
        bias[c] = b;
    }
}

// ---------------- cast x (fp32) -> bf16 row-major --------------------------
__global__ __launch_bounds__(256) void cast_x_kernel(
    const float* __restrict__ x, unsigned short* __restrict__ xb, int n8)
{
    const int i = blockIdx.x * 256 + threadIdx.x;
    if (i >= n8) return;
    const float4 a = ((const float4*)x)[i * 2];
    const float4 b = ((const float4*)x)[i * 2 + 1];
    uint4 o;
    o.x = (unsigned int)f2bf(a.x) | ((unsigned int)f2bf(a.y) << 16);
    o.y = (unsigned int)f2bf(a.z) | ((unsigned int)f2bf(a.w) << 16);
    o.z = (unsigned int)f2bf(b.x) | ((unsigned int)f2bf(b.y) << 16);
    o.w = (unsigned int)f2bf(b.z) | ((unsigned int)f2bf(b.w) << 16);
    ((uint4*)xb)[i] = o;
}

// ---------------- MFMA pre-GEMM: [N x 128] @ [128 x 576] -------------------
// grid (ceil(N/64), 2); 256 thr = 4 waves; wave does 16 rows x 288 cols.
// q, skip, qe in fp32; k|v interleaved bf16 kvb[N][256] (k: 0..127, v: 128..255).
__global__ __launch_bounds__(256) void pre_mfma_kernel(
    const unsigned short* __restrict__ xb, const unsigned short* __restrict__ Bp,
    const float* __restrict__ bias,
    float* __restrict__ q, unsigned short* __restrict__ kvb,
    float* __restrict__ skip, float* __restrict__ qe, int n_nodes)
{
    const int wave = threadIdx.x >> 6, lane = threadIdx.x & 63;
    const int l16 = lane & 15, quad = lane >> 4;
    const int row0 = blockIdx.x * 64 + wave * 16;

    const unsigned short* xr = xb + (size_t)(row0 + l16) * 128 + quad * 8;
    bf16x8 A[4];
#pragma unroll
    for (int kk = 0; kk < 4; ++kk) A[kk] = *(const bf16x8*)(xr + kk * 32);

    const int t0 = blockIdx.y * 18;
    f32x4 acc[18];
#pragma unroll
    for (int t = 0; t < 18; ++t) acc[t] = (f32x4){0.f, 0.f, 0.f, 0.f};

#pragma unroll
    for (int t = 0; t < 18; ++t) {
        const unsigned short* bp = Bp + (size_t)((((t0 + t) * 16 + l16) * 4 + quad)) * 8;
#pragma unroll
        for (int kk = 0; kk < 4; ++kk) {
            bf16x8 B = *(const bf16x8*)(bp + kk * 18432);
            acc[t] = __builtin_amdgcn_mfma_f32_16x16x32_bf16(A[kk], B, acc[t], 0, 0, 0);
        }
    }

#pragma unroll
    for (int t = 0; t < 18; ++t) {
        const int c = (t0 + t) * 16 + l16;
        const float bia = bias[c];
        if (c >= 128 && c < 384) {
            const int cl = c - 128;   // k -> cols 0..127, v -> cols 128..255
#pragma unroll
            for (int r = 0; r < 4; ++r) {
                const int gr = row0 + quad * 4 + r;
                if (gr < n_nodes) kvb[(size_t)gr * 256 + cl] = f2bf(acc[t][r] + bia);
            }
        } else {
            float* dst; int cl, stride;
            if (c < 128)      { dst = q;    cl = c;       stride = 128; }
            else if (c < 512) { dst = skip; cl = c - 384; stride = 128; }
            else              { dst = qe;   cl = c - 512; stride = 64;  }
#pragma unroll
            for (int r = 0; r < 4; ++r) {
                const int gr = row0 + quad * 4 + r;
                if (gr < n_nodes) dst[(size_t)gr * stride + cl] = acc[t][r] + bia;
            }
        }
    }
}

// ---------------- CSR build ------------------------------------------------
__global__ __launch_bounds__(256) void hist_kernel(
    const int* __restrict__ ei, int* __restrict__ cnt, int nE)
{
    int e = blockIdx.x * 256 + threadIdx.x;
    if (e >= nE) return;
    atomicAdd(&cnt[ei[nE + e]], 1);
}

__global__ __launch_bounds__(256) void scan1_kernel(
    const int* __restrict__ cnt, int* __restrict__ offs,
    int* __restrict__ blksum, int n)
{
    __shared__ int tmp[256];
    const int t = threadIdx.x;
    const int base = blockIdx.x * 1024 + t * 4;
    int v0 = (base + 0 < n) ? cnt[base + 0] : 0;
    int v1 = (base + 1 < n) ? cnt[base + 1] : 0;
    int v2 = (base + 2 < n) ? cnt[base + 2] : 0;
    int v3 = (base + 3 < n) ? cnt[base + 3] : 0;
    const int s = v0 + v1 + v2 + v3;
    tmp[t] = s;
    __syncthreads();
    for (int ofs = 1; ofs < 256; ofs <<= 1) {
        int val = (t >= ofs) ? tmp[t - ofs] : 0;
        __syncthreads();
        tmp[t] += val;
        __syncthreads();
    }
    const int excl = tmp[t] - s;
    if (base + 0 < n) offs[base + 0] = excl;
    if (base + 1 < n) offs[base + 1] = excl + v0;
    if (base + 2 < n) offs[base + 2] = excl + v0 + v1;
    if (base + 3 < n) offs[base + 3] = excl + v0 + v1 + v2;
    if (t == 255) blksum[blockIdx.x] = tmp[255];
}

__global__ __launch_bounds__(64) void scan2_kernel(
    int* __restrict__ offs, int* __restrict__ cursor,
    const int* __restrict__ blksum, int n, int nblk)
{
    const int t = threadIdx.x;
    const int b = blockIdx.x;
    int vb = (t < b) ? blksum[t] : 0;
    int va = (t < nblk) ? blksum[t] : 0;
#pragma unroll
    for (int o = 32; o; o >>= 1) { vb += __shfl_xor(vb, o, 64); va += __shfl_xor(va, o, 64); }
    const int boff = vb;
    for (int i = b * 1024 + t; i < (b + 1) * 1024 && i < n; i += 64) {
        int val = offs[i] + boff;
        offs[i] = val;
        cursor[i] = val;
    }
    if (b == 0 && t == 0) offs[n] = va;
}

// ---------------- scatter: build csrsrc + ea permuted to slot order (bf16) -
// one 16-lane group per edge; lane0 claims the slot, group copies ea row.
__global__ __launch_bounds__(256) void scatter_ea_kernel(
    const int* __restrict__ ei, int* __restrict__ cursor,
    const float* __restrict__ ea,
    int* __restrict__ csrsrc, unsigned short* __restrict__ eac, int nE)
{
    const int g = (blockIdx.x * 256 + threadIdx.x) >> 4;
    if (g >= nE) return;
    const int lane = threadIdx.x & 63;
    const int l16 = lane & 15;
    int slot = 0;
    if (l16 == 0) {
        const int dd = ei[nE + g];
        slot = atomicAdd(&cursor[dd], 1);
        csrsrc[slot] = ei[g];
    }
    slot = __shfl(slot, lane & 48, 64);   // broadcast from group's lane 0
    const float4 e4 = ((const float4*)(ea + (size_t)g * ED))[l16];
    ushort4 o;
    o.x = f2bf(e4.x); o.y = f2bf(e4.y); o.z = f2bf(e4.z); o.w = f2bf(e4.w);
    ((ushort4*)eac)[(size_t)slot * 16 + l16] = o;
}

// ---------------- fused attention: alpha + softmax + aggregate -------------
// persistent waves, 1 node per wave; 16 lanes per edge, 4 edges/slot,
// 3 slots (12 edges) of data in flight, src indices prefetched one loop
// iteration ahead of their dependent kv gathers.
// y = agg/lsum + skip written IN PLACE into skip buffer; t/lsum -> tn.
__global__ __launch_bounds__(256, 5) void attn_kernel(
    const int* __restrict__ rowptr, const int* __restrict__ csrsrc,
    const unsigned short* __restrict__ eac,
    const float* __restrict__ q, const float* __restrict__ qe,
    const unsigned short* __restrict__ kvb,
    float* __restrict__ skip_y, float* __restrict__ tn,
    int n_nodes, int nwaves)
{
    const int tid = threadIdx.x;
    const int lane = tid & 63;
    const int grp = lane >> 4, l16 = lane & 15;
    const int wid = blockIdx.x * 4 + (tid >> 6);

#define AT_LDSRC(P, II) do { \
        const int _i = (II) + grp; \
        P##s = csrsrc[_i < end ? _i : beg]; \
    } while (0)
#define AT_LDDATA(P, II) do { \
        const int _i = (II) + grp; \
        const int _ic = _i < end ? _i : beg; \
        const unsigned short* _kv = kvb + (size_t)P##s * 256 + l16 * 8; \
        P##k = *(const bf16x8*)(_kv); \
        P##v = *(const bf16x8*)(_kv + 128); \
        P##e = ((const ushort4*)eac)[(size_t)_ic * 16 + l16]; \
    } while (0)
#define AT_ACC(P, II) do { \
        const float ef0 = bf2f(P##e.x), ef1 = bf2f(P##e.y); \
        const float ef2 = bf2f(P##e.z), ef3 = bf2f(P##e.w); \
        float _p = qa.x * bf2f((unsigned short)P##k[0]) \
                 + qa.y * bf2f((unsigned short)P##k[1]) \
                 + qa.z * bf2f((unsigned short)P##k[2]) \
                 + qa.w * bf2f((unsigned short)P##k[3]) \
                 + qb.x * bf2f((unsigned short)P##k[4]) \
                 + qb.y * bf2f((unsigned short)P##k[5]) \
                 + qb.z * bf2f((unsigned short)P##k[6]) \
                 + qb.w * bf2f((unsigned short)P##k[7]) \
                 + qe4.x * ef0 + qe4.y * ef1 + qe4.z * ef2 + qe4.w * ef3; \
        _p += __shfl_xor(_p, 8, 64); \
        _p += __shfl_xor(_p, 4, 64); \
        _p += __shfl_xor(_p, 2, 64); \
        _p += __shfl_xor(_p, 1, 64); \
        const float _w = ((II) + grp < end) ? __expf(_p * 0.08838834764831845f) : 0.f; \
        a0 += _w * bf2f((unsigned short)P##v[0]); \
        a1 += _w * bf2f((unsigned short)P##v[1]); \
        a2 += _w * bf2f((unsigned short)P##v[2]); \
        a3 += _w * bf2f((unsigned short)P##v[3]); \
        a4 += _w * bf2f((unsigned short)P##v[4]); \
        a5 += _w * bf2f((unsigned short)P##v[5]); \
        a6 += _w * bf2f((unsigned short)P##v[6]); \
        a7 += _w * bf2f((unsigned short)P##v[7]); \
        t0 += _w * ef0; t1 += _w * ef1; t2 += _w * ef2; t3 += _w * ef3; \
        lsum += _w; \
    } while (0)

    for (int d = wid; d < n_nodes; d += nwaves) {
        const int beg = rowptr[d], end = rowptr[d + 1];
        float a0 = 0, a1 = 0, a2 = 0, a3 = 0, a4 = 0, a5 = 0, a6 = 0, a7 = 0;
        float t0 = 0, t1 = 0, t2 = 0, t3 = 0, lsum = 0;

        const float4 qa  = *(const float4*)(q + (size_t)d * D + l16 * 8);
        const float4 qb  = *(const float4*)(q + (size_t)d * D + l16 * 8 + 4);
        const float4 qe4 = ((const float4*)(qe + (size_t)d * ED))[l16];

        if (beg < end) {
            int As, Bs, Cs;
            bf16x8 Ak, Av, Bk, Bv, Ck, Cv;
            ushort4 Ae, Be, Ce;
            AT_LDSRC(A, beg); AT_LDSRC(B, beg + 4); AT_LDSRC(C, beg + 8);
            AT_LDDATA(A, beg); AT_LDDATA(B, beg + 4); AT_LDDATA(C, beg + 8);
            AT_LDSRC(A, beg + 12); AT_LDSRC(B, beg + 16); AT_LDSRC(C, beg + 20);
            for (int i = beg; i < end; i += 12) {
                AT_ACC(A, i);
                if (i + 12 < end) { AT_LDDATA(A, i + 12); AT_LDSRC(A, i + 24); }
                AT_ACC(B, i + 4);
                if (i + 16 < end) { AT_LDDATA(B, i + 16); AT_LDSRC(B, i + 28); }
                AT_ACC(C, i + 8);
                if (i + 20 < end) { AT_LDDATA(C, i + 20); AT_LDSRC(C, i + 32); }
            }
        }
        // merge the 4 groups
#pragma unroll
        for (int off = 16; off <= 32; off <<= 1) {
            a0 += __shfl_xor(a0, off, 64); a1 += __shfl_xor(a1, off, 64);
            a2 += __shfl_xor(a2, off, 64); a3 += __shfl_xor(a3, off, 64);
            a4 += __shfl_xor(a4, off, 64); a5 += __shfl_xor(a5, off, 64);
            a6 += __shfl_xor(a6, off, 64); a7 += __shfl_xor(a7, off, 64);
            t0 += __shfl_xor(t0, off, 64); t1 += __shfl_xor(t1, off, 64);
            t2 += __shfl_xor(t2, off, 64); t3 += __shfl_xor(t3, off, 64);
            lsum += __shfl_xor(lsum, off, 64);
        }
        const float inv = 1.f / fmaxf(lsum, 1e-16f);
        if (grp == 0) {
            float4* sp = (float4*)(skip_y + (size_t)d * D);
            const float4 s0 = sp[l16 * 2], s1 = sp[l16 * 2 + 1];
            sp[l16 * 2] = make_float4(a0 * inv + s0.x, a1 * inv + s0.y,
                                      a2 * inv + s0.z, a3 * inv + s0.w);
            sp[l16 * 2 + 1] = make_float4(a4 * inv + s1.x, a5 * inv + s1.y,
                                          a6 * inv + s1.z, a7 * inv + s1.w);
        } else if (grp == 1) {
            ((float4*)(tn + (size_t)d * ED))[l16] =
                make_float4(t0 * inv, t1 * inv, t2 * inv, t3 * inv);
        }
    }
#undef AT_LDSRC
#undef AT_LDDATA
#undef AT_ACC
}

// ---------------- epilogue: out = y + t@We (+relu+bf16 for L1) -------------
// block: 256 thr = 16 nodes x 16 col-groups of 8.
template<bool L1>
__global__ __launch_bounds__(256) void out_we_kernel(
    const float* __restrict__ y, const float* __restrict__ tn,
    const float* __restrict__ We, float* __restrict__ outf,
    unsigned short* __restrict__ outb, int n_nodes)
{
    __shared__ float WeS[ED * D];          // 32 KB, [j][c]
    __shared__ float tS[16 * (ED + 1)];    // padded rows
    const int tid = threadIdx.x;
    for (int i = tid; i < ED * D / 4; i += 256)
        ((float4*)WeS)[i] = ((const float4*)We)[i];
    const int n0 = blockIdx.x * 16;
    for (int i = tid; i < 16 * ED; i += 256) {
        const int r = i >> 6, c = i & 63;
        const int n = n0 + r;
        tS[r * (ED + 1) + c] = (n < n_nodes) ? tn[(size_t)n * ED + c] : 0.f;
    }
    __syncthreads();
    const int r = tid >> 4;
    const int n = n0 + r;
    if (n >= n_nodes) return;
    const int c0 = (tid & 15) * 8;
    const float* tr = tS + r * (ED + 1);
    float acc0 = 0, acc1 = 0, acc2 = 0, acc3 = 0, acc4 = 0, acc5 = 0, acc6 = 0, acc7 = 0;
#pragma unroll 8
    for (int j = 0; j < ED; ++j) {
        const float tv = tr[j];
        const float4 wA = *(const float4*)(WeS + j * D + c0);
        const float4 wB = *(const float4*)(WeS + j * D + c0 + 4);
        acc0 += tv * wA.x; acc1 += tv * wA.y; acc2 += tv * wA.z; acc3 += tv * wA.w;
        acc4 += tv * wB.x; acc5 += tv * wB.y; acc6 += tv * wB.z; acc7 += tv * wB.w;
    }
    const float4 yA = *(const float4*)(y + (size_t)n * D + c0);
    const float4 yB = *(const float4*)(y + (size_t)n * D + c0 + 4);
    float r0 = acc0 + yA.x, r1 = acc1 + yA.y, r2 = acc2 + yA.z, r3 = acc3 + yA.w;
    float r4 = acc4 + yB.x, r5 = acc5 + yB.y, r6 = acc6 + yB.z, r7 = acc7 + yB.w;
    if (L1) {
        r0 = fmaxf(r0, 0.f); r1 = fmaxf(r1, 0.f);
        r2 = fmaxf(r2, 0.f); r3 = fmaxf(r3, 0.f);
        r4 = fmaxf(r4, 0.f); r5 = fmaxf(r5, 0.f);
        r6 = fmaxf(r6, 0.f); r7 = fmaxf(r7, 0.f);
        uint4 o;
        o.x = (unsigned int)f2bf(r0) | ((unsigned int)f2bf(r1) << 16);
        o.y = (unsigned int)f2bf(r2) | ((unsigned int)f2bf(r3) << 16);
        o.z = (unsigned int)f2bf(r4) | ((unsigned int)f2bf(r5) << 16);
        o.w = (unsigned int)f2bf(r6) | ((unsigned int)f2bf(r7) << 16);
        ((uint4*)(outb + (size_t)n * D))[tid & 15] = o;
    } else {
        float4* op = (float4*)(outf + (size_t)n * D);
        op[(tid & 15) * 2] = make_float4(r0, r1, r2, r3);
        op[(tid & 15) * 2 + 1] = make_float4(r4, r5, r6, r7);
    }
}

// ---------------------------------------------------------------------------
extern "C" void kernel_launch(void* const* d_in, const int* in_sizes, int n_in,
                              void* d_out, int out_size, void* d_ws, size_t ws_size,
                              hipStream_t stream) {
    const float* x   = (const float*)d_in[0];
    const int*   ei  = (const int*)d_in[1];
    const float* ea  = (const float*)d_in[2];
    const float* Wq1 = (const float*)d_in[3];  const float* bq1 = (const float*)d_in[4];
    const float* Wk1 = (const float*)d_in[5];  const float* bk1 = (const float*)d_in[6];
    const float* Wv1 = (const float*)d_in[7];  const float* bv1 = (const float*)d_in[8];
    const float* We1 = (const float*)d_in[9];
    const float* Ws1 = (const float*)d_in[10]; const float* bs1 = (const float*)d_in[11];
    const float* Wq2 = (const float*)d_in[12]; const float* bq2 = (const float*)d_in[13];
    const float* Wk2 = (const float*)d_in[14]; const float* bk2 = (const float*)d_in[15];
    const float* Wv2 = (const float*)d_in[16]; const float* bv2 = (const float*)d_in[17];
    const float* We2 = (const float*)d_in[18];
    const float* Ws2 = (const float*)d_in[19]; const float* bs2 = (const float*)d_in[20];

    const int N_ = in_sizes[0] / D;
    const int E_ = in_sizes[1] / 2;
    const int Npad = ((N_ + 63) / 64) * 64;

    // workspace layout
    float* ws   = (float*)d_ws;
    float* q    = ws;                                   // [Npad][128] f32
    float* skip = q + (size_t)Npad * D;                 // [Npad][128] f32 (y in place)
    float* qe   = skip + (size_t)Npad * D;              // [Npad][64]  f32
    float* tn   = qe + (size_t)Npad * ED;               // [Npad][64]  f32
    unsigned short* kvb = (unsigned short*)(tn + (size_t)Npad * ED); // [Npad][256] bf16 (k|v)
    unsigned short* xb = kvb + (size_t)Npad * 256;      // [Npad][128] bf16
    unsigned short* Bp1 = xb + (size_t)Npad * D;        // 73728 ushorts
    unsigned short* Bp2 = Bp1 + 73728;
    float* bias1 = (float*)(Bp2 + 73728);
    float* bias2 = bias1 + 576;
    float* Wqe1  = bias2 + 576;
    float* bqe1  = Wqe1 + D * ED;
    float* Wqe2  = bqe1 + ED;
    float* bqe2  = Wqe2 + D * ED;
    unsigned short* eac = (unsigned short*)(bqe2 + ED); // [E][64] bf16, slot order
    int* cnt    = (int*)(eac + (size_t)E_ * ED);
    int* offs   = cnt  + N_;
    int* blksum = offs + N_ + 1;
    int* csrsrc = blksum + 64;                          // [E] int (src only)
    float* out  = (float*)d_out;

    const int eblk256 = (E_ + 255) / 256;
    const int eblk16  = (E_ * 16 + 255) / 256;
    const int sblk    = (N_ + 1023) / 1024;
    const int gpre    = Npad / 64;
    const int ablk    = 2048;                           // 8192 waves = full slot budget
    const int nwaves  = ablk * 4;
    const int oblk    = (N_ + 15) / 16;

    // ---- CSR build + ea permute/cast (shared by both layers) ----
    hipMemsetAsync(cnt, 0, (size_t)N_ * sizeof(int), stream);
    hist_kernel<<<eblk256, 256, 0, stream>>>(ei, cnt, E_);
    scan1_kernel<<<sblk, 256, 0, stream>>>(cnt, offs, blksum, N_);
    scan2_kernel<<<sblk, 64, 0, stream>>>(offs, cnt, blksum, N_, sblk);
    scatter_ea_kernel<<<eblk16, 256, 0, stream>>>(ei, cnt, ea, csrsrc, eac, E_);

    // ---- weight prep ----
    fuse_we_kernel<<<65, 128, 0, stream>>>(Wq1, bq1, We1, Wqe1, bqe1);
    fuse_we_kernel<<<65, 128, 0, stream>>>(Wq2, bq2, We2, Wqe2, bqe2);
    pack_weights_kernel<<<39, 256, 0, stream>>>(Wq1, Wk1, Wv1, Ws1, Wqe1,
                                                bq1, bk1, bv1, bs1, bqe1, Bp1, bias1);
    pack_weights_kernel<<<39, 256, 0, stream>>>(Wq2, Wk2, Wv2, Ws2, Wqe2,
                                                bq2, bk2, bv2, bs2, bqe2, Bp2, bias2);
    cast_x_kernel<<<(N_ * D / 8 + 255) / 256, 256, 0, stream>>>(x, xb, N_ * D / 8);

    // ---- layer 1 ----
    pre_mfma_kernel<<<dim3(gpre, 2), 256, 0, stream>>>(xb, Bp1, bias1,
                                                       q, kvb, skip, qe, N_);
    attn_kernel<<<ablk, 256, 0, stream>>>(offs, csrsrc, eac, q, qe, kvb,
                                          skip, tn, N_, nwaves);
    out_we_kernel<true><<<oblk, 256, 0, stream>>>(skip, tn, We1, nullptr, xb, N_);

    // ---- layer 2 (h lives as bf16 in xb) ----
    pre_mfma_kernel<<<dim3(gpre, 2), 256, 0, stream>>>(xb, Bp2, bias2,
                                                       q, kvb, skip, qe, N_);
    attn_kernel<<<ablk, 256, 0, stream>>>(offs, csrsrc, eac, q, qe, kvb,
                                          skip, tn, N_, nwaves);
    out_we_kernel<false><<<oblk, 256, 0, stream>>>(skip, tn, We2, out, nullptr, N_);
}